// Round 1
// baseline (553.592 us; speedup 1.0000x reference)
//
#include <hip/hip_runtime.h>
#include <hip/hip_bf16.h>
#include <math.h>

#define HDIM 512
#define LSEQ 1024
#define BSZ  4

typedef __attribute__((ext_vector_type(8))) short short8;
typedef __attribute__((ext_vector_type(4))) float floatx4;

// ---------------- LayerNorm: one wave per (b,t) row ----------------
__global__ __launch_bounds__(64) void ln_kernel(const float* __restrict__ x,
    const float* __restrict__ w, const float* __restrict__ b, float* __restrict__ xn) {
  int row = blockIdx.x;           // b*L + t   (4096 rows)
  int lane = threadIdx.x;
  const float* xr = x + (size_t)row * HDIM;
  float4 v0 = ((const float4*)xr)[lane];
  float4 v1 = ((const float4*)xr)[lane + 64];
  float s  = v0.x + v0.y + v0.z + v0.w + v1.x + v1.y + v1.z + v1.w;
  float ss = v0.x*v0.x + v0.y*v0.y + v0.z*v0.z + v0.w*v0.w
           + v1.x*v1.x + v1.y*v1.y + v1.z*v1.z + v1.w*v1.w;
  #pragma unroll
  for (int m = 1; m < 64; m <<= 1) { s += __shfl_xor(s, m); ss += __shfl_xor(ss, m); }
  float mu   = s * (1.0f / HDIM);
  float var  = ss * (1.0f / HDIM) - mu * mu;
  float rstd = rsqrtf(var + 1e-5f);
  float4 w0 = ((const float4*)w)[lane];
  float4 w1 = ((const float4*)w)[lane + 64];
  float4 b0 = ((const float4*)b)[lane];
  float4 b1 = ((const float4*)b)[lane + 64];
  float4 o0, o1;
  o0.x = (v0.x - mu) * rstd * w0.x + b0.x;
  o0.y = (v0.y - mu) * rstd * w0.y + b0.y;
  o0.z = (v0.z - mu) * rstd * w0.z + b0.z;
  o0.w = (v0.w - mu) * rstd * w0.w + b0.w;
  o1.x = (v1.x - mu) * rstd * w1.x + b1.x;
  o1.y = (v1.y - mu) * rstd * w1.y + b1.y;
  o1.z = (v1.z - mu) * rstd * w1.z + b1.z;
  o1.w = (v1.w - mu) * rstd * w1.w + b1.w;
  float* xo = xn + (size_t)row * HDIM;
  ((float4*)xo)[lane] = o0;
  ((float4*)xo)[lane + 64] = o1;
}

// ---------------- Transpose xn [B,L,H] -> xn_t [B,H,L] ----------------
__global__ __launch_bounds__(256) void transpose_kernel(const float* __restrict__ xn,
                                                        float* __restrict__ xnt) {
  __shared__ float tile[64][65];
  int ht = blockIdx.x;   // h tile (8)
  int lt = blockIdx.y;   // l tile (16)
  int b  = blockIdx.z;
  int tid = threadIdx.x;
  #pragma unroll
  for (int q = 0; q < 16; q++) {
    int idx = q * 256 + tid;
    int r = idx >> 6, c = idx & 63;                 // r: l-offset, c: h-offset
    tile[r][c] = xn[((size_t)(b * LSEQ + lt * 64 + r)) * HDIM + ht * 64 + c];
  }
  __syncthreads();
  #pragma unroll
  for (int q = 0; q < 16; q++) {
    int idx = q * 256 + tid;
    int r = idx >> 6, c = idx & 63;                 // r: h-offset, c: l-offset
    xnt[((size_t)(b * HDIM + ht * 64 + r)) * LSEQ + lt * 64 + c] = tile[c][r];
  }
}

// ---------------- DPLR coefficient setup (single wave) ----------------
// Ab = diag(dab) + u * r^T ;  Bb = 2*(dinv*b - u*(gamma/(1+beta)))
__global__ __launch_bounds__(64) void setup_kernel(
    const float* __restrict__ lre, const float* __restrict__ lim,
    const float* __restrict__ pre, const float* __restrict__ pim,
    const float* __restrict__ bre, const float* __restrict__ bim,
    const float* __restrict__ cre, const float* __restrict__ cim,
    const float* __restrict__ logstep, float* __restrict__ coef) {
  int n = threadIdx.x;
  float step = expf(logstep[0]);
  float g = 2.0f / step;
  float lr = lre[n], li = lim[n];
  float pr = pre[n], pi = pim[n];
  float br = bre[n], bi = bim[n];
  float cr = cre[n], ci = cim[n];
  // dinv = 1/(g - lam) = ((g-lr) + i*li)/((g-lr)^2 + li^2)
  float den  = (g - lr) * (g - lr) + li * li;
  float dinr = (g - lr) / den, dini = li / den;
  // dab = (g + lam) * dinv
  float dabr = (g + lr) * dinr - li * dini;
  float dabi = (g + lr) * dini + li * dinr;
  // u = dinv * p
  float ur = dinr * pr - dini * pi;
  float ui = dinr * pi + dini * pr;
  // q = conj(p) * dinv
  float qr = pr * dinr + pi * dini;
  float qi = pr * dini - pi * dinr;
  // beta = sum |p|^2 * dinv
  float pm2 = pr * pr + pi * pi;
  float betr = pm2 * dinr, beti = pm2 * dini;
  // gamma = sum q * b
  float gar = qr * br - qi * bi;
  float gai = qr * bi + qi * br;
  #pragma unroll
  for (int m = 1; m < 64; m <<= 1) {
    betr += __shfl_xor(betr, m); beti += __shfl_xor(beti, m);
    gar  += __shfl_xor(gar, m);  gai  += __shfl_xor(gai, m);
  }
  float obr = 1.0f + betr, obi = beti;
  float ob2 = obr * obr + obi * obi;
  // k = -2g/(1+beta)
  float kr = -2.0f * g * obr / ob2;
  float ki =  2.0f * g * obi / ob2;
  // r = k * q
  float rr = kr * qr - ki * qi;
  float ri = kr * qi + ki * qr;
  // tg = gamma/(1+beta)
  float tgr = (gar * obr + gai * obi) / ob2;
  float tgi = (gai * obr - gar * obi) / ob2;
  // Bb = 2*(dinv*b - u*tg)
  float dbr = dinr * br - dini * bi;
  float dbi = dinr * bi + dini * br;
  float Bbr = 2.0f * (dbr - (ur * tgr - ui * tgi));
  float Bbi = 2.0f * (dbi - (ur * tgi + ui * tgr));
  // cd = c * dab
  float cdr = cr * dabr - ci * dabi;
  float cdi = cr * dabi + ci * dabr;
  // cu = sum c*u ; cB = sum c*Bb
  float cur = cr * ur - ci * ui;
  float cui = cr * ui + ci * ur;
  float cBr = cr * Bbr - ci * Bbi;
  #pragma unroll
  for (int m = 1; m < 64; m <<= 1) {
    cur += __shfl_xor(cur, m); cui += __shfl_xor(cui, m); cBr += __shfl_xor(cBr, m);
  }
  coef[n]         = dabr;  coef[n + 64]  = dabi;
  coef[n + 128]   = ur;    coef[n + 192] = ui;
  coef[n + 256]   = rr;    coef[n + 320] = ri;
  coef[n + 384]   = Bbr;   coef[n + 448] = Bbi;
  coef[n + 512]   = cdr;   coef[n + 576] = cdi;
  if (n == 0) { coef[640] = cur; coef[641] = cui; coef[642] = cBr; }
}

// ---------------- Sequential scan: one wave per (b,h) pair ----------------
__global__ __launch_bounds__(64) void scan_kernel(const float* __restrict__ xnt,
    const float* __restrict__ coef, float* __restrict__ ys) {
  int lane = threadIdx.x;
  int bh = blockIdx.x;                       // b*H + h  (2048)
  const float dabr = coef[lane],       dabi = coef[lane + 64];
  const float ur   = coef[lane + 128], ui   = coef[lane + 192];
  const float rr   = coef[lane + 256], ri   = coef[lane + 320];
  const float Bbr  = coef[lane + 384], Bbi  = coef[lane + 448];
  const float cdr  = coef[lane + 512], cdi  = coef[lane + 576];
  const float cur = coef[640], cui = coef[641], cBr = coef[642];
  const float* u_row = xnt + (size_t)bh * LSEQ;
  float* y_row = ys + (size_t)bh * LSEQ;
  float sre = 0.0f, sim = 0.0f;
  for (int w = 0; w < 16; w++) {
    float uvec = u_row[w * 64 + lane];
    float ykeep = 0.0f;
    #pragma unroll 8
    for (int tt = 0; tt < 64; tt++) {
      float ut = __shfl(uvec, tt);
      // per-lane reduction inputs: R = sum r*s (complex), S2re = Re(sum cd*s)
      float a  = rr * sre - ri * sim;
      float bb = rr * sim + ri * sre;
      float e  = cdr * sre - cdi * sim;
      #pragma unroll
      for (int m = 1; m < 64; m <<= 1) {
        a  += __shfl_xor(a, m);
        bb += __shfl_xor(bb, m);
        e  += __shfl_xor(e, m);
      }
      float yt = e + cur * a - cui * bb + ut * cBr;
      float nsre = dabr * sre - dabi * sim + ur * a - ui * bb + Bbr * ut;
      float nsim = dabr * sim + dabi * sre + ur * bb + ui * a + Bbi * ut;
      sre = nsre; sim = nsim;
      ykeep = (lane == tt) ? yt : ykeep;
    }
    y_row[w * 64 + lane] = ykeep;
  }
}

// ---------------- A-prep: A_bf16[b,t,h] = gelu(ys[b,h,t] + d*xn[b,t,h]) ----------------
__global__ __launch_bounds__(256) void aprep_kernel(const float* __restrict__ ys,
    const float* __restrict__ xn, const float* __restrict__ dptr,
    __hip_bfloat16* __restrict__ A) {
  __shared__ float tile[64][65];
  int tt = blockIdx.x;  // t tile (16)
  int ht = blockIdx.y;  // h tile (8)
  int b  = blockIdx.z;
  int tid = threadIdx.x;
  float d = dptr[0];
  #pragma unroll
  for (int q = 0; q < 16; q++) {
    int idx = q * 256 + tid;
    int r = idx >> 6, c = idx & 63;               // r: h-offset, c: t-offset
    tile[r][c] = ys[((size_t)(b * HDIM + ht * 64 + r)) * LSEQ + tt * 64 + c];
  }
  __syncthreads();
  #pragma unroll
  for (int q = 0; q < 16; q++) {
    int idx = q * 256 + tid;
    int r = idx >> 6, c = idx & 63;               // r: t-offset, c: h-offset
    size_t off = ((size_t)(b * LSEQ + tt * 64 + r)) * HDIM + ht * 64 + c;
    float y = tile[c][r] + d * xn[off];
    float t = tanhf(0.7978845608028654f * (y + 0.044715f * y * y * y));
    float gl = 0.5f * y * (1.0f + t);
    A[off] = __float2bfloat16(gl);
  }
}

// ---------------- Weight convert/stack: Wst[1024][512] bf16 ----------------
__global__ __launch_bounds__(256) void wconv_kernel(const float* __restrict__ w1,
    const float* __restrict__ w2, __hip_bfloat16* __restrict__ Wst) {
  int idx = blockIdx.x * 256 + threadIdx.x;       // 524288
  int n = idx >> 9, k = idx & 511;
  float v = (n < 512) ? w1[n * 512 + k] : w2[(n - 512) * 512 + k];
  Wst[idx] = __float2bfloat16(v);
}

// ---------------- GEMM: C[4096,1024] = A[4096,512] * Wst[1024,512]^T ----------------
__global__ __launch_bounds__(256) void gemm_kernel(const __hip_bfloat16* __restrict__ Abf,
    const __hip_bfloat16* __restrict__ Wst, float* __restrict__ C) {
  __shared__ unsigned short sA[128 * 32];
  __shared__ unsigned short sB[128 * 32];
  int tid = threadIdx.x;
  int lane = tid & 63;
  int wv = tid >> 6;
  int wm = wv >> 1, wn = wv & 1;
  int bm = blockIdx.y, bn = blockIdx.x;
  floatx4 acc[4][4] = {};
  const unsigned short* Ag = (const unsigned short*)Abf + (size_t)(bm * 128) * 512;
  const unsigned short* Bg = (const unsigned short*)Wst + (size_t)(bn * 128) * 512;
  int lrow = tid >> 2;
  int lcol = (tid & 3) * 8;
  int fr = lane & 15, fq = (lane >> 4) * 8;
  for (int kt = 0; kt < 16; kt++) {
    int k0 = kt * 32;
    #pragma unroll
    for (int q = 0; q < 2; q++) {
      int row = lrow + q * 64;
      *(uint4*)&sA[row * 32 + lcol] = *(const uint4*)&Ag[(size_t)row * 512 + k0 + lcol];
      *(uint4*)&sB[row * 32 + lcol] = *(const uint4*)&Bg[(size_t)row * 512 + k0 + lcol];
    }
    __syncthreads();
    short8 af[4], bf[4];
    #pragma unroll
    for (int i = 0; i < 4; i++) {
      af[i] = *(const short8*)&sA[(wm * 64 + i * 16 + fr) * 32 + fq];
      bf[i] = *(const short8*)&sB[(wn * 64 + i * 16 + fr) * 32 + fq];
    }
    #pragma unroll
    for (int i = 0; i < 4; i++)
      #pragma unroll
      for (int j = 0; j < 4; j++)
        acc[i][j] = __builtin_amdgcn_mfma_f32_16x16x32_bf16(af[i], bf[j], acc[i][j], 0, 0, 0);
    __syncthreads();
  }
  int row0 = bm * 128 + wm * 64;
  int col0 = bn * 128 + wn * 64;
  int fc = lane & 15, frq = (lane >> 4) * 4;
  #pragma unroll
  for (int i = 0; i < 4; i++)
    #pragma unroll
    for (int j = 0; j < 4; j++)
      #pragma unroll
      for (int r = 0; r < 4; r++)
        C[(size_t)(row0 + i * 16 + frq + r) * 1024 + col0 + j * 16 + fc] = acc[i][j][r];
}

// ---------------- Final: out = x + (C1 + ob) * sigmoid(C2 + o2b) ----------------
__global__ __launch_bounds__(256) void final_kernel(const float* __restrict__ x,
    const float* __restrict__ C, const float* __restrict__ ob,
    const float* __restrict__ o2b, float* __restrict__ out) {
  int idx = blockIdx.x * 256 + threadIdx.x;
  int i = idx & 511;
  int bt = idx >> 9;
  float c1 = C[(size_t)bt * 1024 + i] + ob[i];
  float c2 = C[(size_t)bt * 1024 + 512 + i] + o2b[i];
  float gate = 1.0f / (1.0f + expf(-c2));
  out[idx] = x[idx] + c1 * gate;
}

extern "C" void kernel_launch(void* const* d_in, const int* in_sizes, int n_in,
                              void* d_out, int out_size, void* d_ws, size_t ws_size,
                              hipStream_t stream) {
  const float* x   = (const float*)d_in[0];
  const float* nw  = (const float*)d_in[1];
  const float* nb  = (const float*)d_in[2];
  const float* lre = (const float*)d_in[3];
  const float* lim = (const float*)d_in[4];
  const float* pre = (const float*)d_in[5];
  const float* pim = (const float*)d_in[6];
  const float* bre = (const float*)d_in[7];
  const float* bim = (const float*)d_in[8];
  const float* cre = (const float*)d_in[9];
  const float* cim = (const float*)d_in[10];
  const float* dsc = (const float*)d_in[11];
  const float* lst = (const float*)d_in[12];
  const float* w1  = (const float*)d_in[13];
  const float* ob  = (const float*)d_in[14];
  const float* w2  = (const float*)d_in[15];
  const float* o2b = (const float*)d_in[16];

  char* ws = (char*)d_ws;
  float* xn  = (float*)(ws);                         // 8 MB
  float* xnt = (float*)(ws + (size_t)(8  << 20));    // 8 MB
  float* ys  = (float*)(ws + (size_t)(16 << 20));    // 8 MB
  __hip_bfloat16* Abuf = (__hip_bfloat16*)(ws + (size_t)(24 << 20)); // 4 MB
  __hip_bfloat16* Wst  = (__hip_bfloat16*)(ws + (size_t)(28 << 20)); // 1 MB
  float* coef = (float*)(ws + (size_t)(29 << 20));   // tiny
  float* C    = (float*)(ws + (size_t)(8 << 20));    // 16 MB, reuses dead xnt+ys
  float* out  = (float*)d_out;

  ln_kernel<<<dim3(4096), dim3(64), 0, stream>>>(x, nw, nb, xn);
  transpose_kernel<<<dim3(8, 16, 4), dim3(256), 0, stream>>>(xn, xnt);
  setup_kernel<<<dim3(1), dim3(64), 0, stream>>>(lre, lim, pre, pim, bre, bim,
                                                 cre, cim, lst, coef);
  wconv_kernel<<<dim3(2048), dim3(256), 0, stream>>>(w1, w2, Wst);
  scan_kernel<<<dim3(2048), dim3(64), 0, stream>>>(xnt, coef, ys);
  aprep_kernel<<<dim3(16, 8, 4), dim3(256), 0, stream>>>(ys, xn, dsc, Abuf);
  gemm_kernel<<<dim3(8, 32), dim3(256), 0, stream>>>(Abuf, Wst, C);
  final_kernel<<<dim3(8192), dim3(256), 0, stream>>>(x, C, ob, o2b, out);
}